// Round 9
// baseline (1227.909 us; speedup 1.0000x reference)
//
#include <hip/hip_runtime.h>
#include <math.h>

// Problem constants (fixed by the reference)
#define NN 50000          // nodes
#define NE 800000         // edges
#define NE2 (NE + NN)     // edges + self loops = 850000
#define INC 64            // in channels
#define EDD 16            // edge dim
#define NH 4              // heads
#define CC 64             // per-head channels
#define HC 256            // H*C
#define NG 2048           // graphs
#define SLOPE 0.2f

typedef float v2f __attribute__((ext_vector_type(2)));
typedef float v4f __attribute__((ext_vector_type(4)));

#define RFL(x) __builtin_amdgcn_readfirstlane(x)

// ---------------- mean edge attr ----------------
__global__ void ea_sum_kernel(const float* __restrict__ ea, float* __restrict__ meansum) {
  __shared__ float part[16];
  if (threadIdx.x < 16) part[threadIdx.x] = 0.f;
  __syncthreads();
  size_t stride = (size_t)gridDim.x * blockDim.x;          // multiple of 16
  size_t i = (size_t)blockIdx.x * blockDim.x + threadIdx.x;
  int cls = (int)(i & 15);                                  // constant along loop
  float s = 0.f;
  const size_t total = (size_t)NE * EDD;
  for (; i < total; i += stride) s += ea[i];
  atomicAdd(&part[cls], s);
  __syncthreads();
  if (threadIdx.x < 16) atomicAdd(&meansum[threadIdx.x], part[threadIdx.x]);
}

__global__ void ea_div_kernel(const float* __restrict__ meansum, float* __restrict__ meanea) {
  if (threadIdx.x < 16) meanea[threadIdx.x] = meansum[threadIdx.x] * (1.0f / NE);
}

// ---------------- CSR build (group edges by dst) ----------------
__global__ void count_dst_kernel(const int* __restrict__ ei, int* __restrict__ counts) {
  int e = blockIdx.x * blockDim.x + threadIdx.x;
  if (e >= NE2) return;
  int d = (e < NE) ? ei[NE + e] : (e - NE);
  atomicAdd(&counts[d], 1);
}

// 3-phase exclusive scan over n counts (n <= 256*256)
__global__ void scan_partial_kernel(const int* __restrict__ counts, int n,
                                    int* __restrict__ excl, int* __restrict__ btot) {
  int b = blockIdx.x;
  int i = b * 256 + threadIdx.x;
  int v = (i < n) ? counts[i] : 0;
  int lane = threadIdx.x & 63;
  int incl = v;
#pragma unroll
  for (int off = 1; off < 64; off <<= 1) {
    int t = __shfl_up(incl, off, 64);
    if (lane >= off) incl += t;
  }
  __shared__ int wtot[4];
  int w = threadIdx.x >> 6;
  if (lane == 63) wtot[w] = incl;
  __syncthreads();
  int woff = 0;
#pragma unroll
  for (int k = 0; k < 4; ++k) woff += (k < w) ? wtot[k] : 0;
  incl += woff;
  if (i < n) excl[i] = incl - v;
  if (threadIdx.x == 255) btot[b] = incl;
}

__global__ void scan_btot_kernel(int* __restrict__ btot, int nb, int* __restrict__ totp) {
  __shared__ int buf[256];
  int v = (threadIdx.x < nb) ? btot[threadIdx.x] : 0;
  buf[threadIdx.x] = v;
  __syncthreads();
  for (int off = 1; off < 256; off <<= 1) {
    int t = (threadIdx.x >= off) ? buf[threadIdx.x - off] : 0;
    __syncthreads();
    buf[threadIdx.x] += t;
    __syncthreads();
  }
  if (threadIdx.x < nb) btot[threadIdx.x] = buf[threadIdx.x] - v;  // exclusive
  if (threadIdx.x == 0) *totp = buf[nb - 1];                       // grand total
}

__global__ void scan_add_kernel(int* __restrict__ excl, int n, const int* __restrict__ btot) {
  int i = blockIdx.x * 256 + threadIdx.x;
  if (i < n) excl[i] += btot[blockIdx.x];
}

// edge record: x = byte offset into ea (e*64) or -1 for self-loop;
//              y = byte offset of src row in xl (s*1024)
__global__ void fill_kernel(const int* __restrict__ ei, const int* __restrict__ row_ptr,
                            int* __restrict__ cursor, int2* __restrict__ edg) {
  int e = blockIdx.x * blockDim.x + threadIdx.x;
  if (e >= NE2) return;
  int d, s, eo;
  if (e < NE) { d = ei[NE + e]; s = ei[e]; eo = e << 6; }
  else        { d = e - NE;     s = d;     eo = -1;     }
  int pos = row_ptr[d] + atomicAdd(&cursor[d], 1);
  edg[pos] = make_int2(eo, s << 10);
}

// ---------------- f32 GEMM: Y[n,256] = X[n,K] @ W[K,256] ----------------
// BM=64, BN=128, BK=16, 256 threads, 4x8 per-thread tile.
__global__ __launch_bounds__(256, 4) void gemm_kernel(const float* __restrict__ X,
                                                      const float* __restrict__ W,
                                                      float* __restrict__ Y,
                                                      int n, int K) {
  __shared__ float Xs[16][64];
  __shared__ float Ws[16][128];
  const int tid = threadIdx.x;
  const int row0 = blockIdx.x * 64;
  const int col0 = blockIdx.y * 128;
  const int tr = tid >> 4, tc = tid & 15;
  float acc[4][8] = {};
  for (int k0 = 0; k0 < K; k0 += 16) {
    // stage X tile (transposed to [k][m])
    {
      int m = tid >> 2, kq = tid & 3;
      float4 v = make_float4(0.f, 0.f, 0.f, 0.f);
      int r = row0 + m;
      if (r < n) v = *(const float4*)(X + (size_t)r * K + k0 + kq * 4);
      Xs[kq * 4 + 0][m] = v.x; Xs[kq * 4 + 1][m] = v.y;
      Xs[kq * 4 + 2][m] = v.z; Xs[kq * 4 + 3][m] = v.w;
    }
    // stage W tile
    {
      int kk = tid >> 4, nq = tid & 15;
      float4 v0 = *(const float4*)(W + (size_t)(k0 + kk) * HC + col0 + nq * 8);
      float4 v1 = *(const float4*)(W + (size_t)(k0 + kk) * HC + col0 + nq * 8 + 4);
      *(float4*)(&Ws[kk][nq * 8])     = v0;
      *(float4*)(&Ws[kk][nq * 8 + 4]) = v1;
    }
    __syncthreads();
#pragma unroll
    for (int k = 0; k < 16; ++k) {
      float4 a  = *(const float4*)(&Xs[k][tr * 4]);
      float4 b0 = *(const float4*)(&Ws[k][tc * 8]);
      float4 b1 = *(const float4*)(&Ws[k][tc * 8 + 4]);
      float av[4] = {a.x, a.y, a.z, a.w};
      float bv[8] = {b0.x, b0.y, b0.z, b0.w, b1.x, b1.y, b1.z, b1.w};
#pragma unroll
      for (int i = 0; i < 4; ++i)
#pragma unroll
        for (int jj = 0; jj < 8; ++jj) acc[i][jj] += av[i] * bv[jj];
    }
    __syncthreads();
  }
#pragma unroll
  for (int i = 0; i < 4; ++i) {
    int r = row0 + tr * 4 + i;
    if (r < n) {
      *(float4*)(Y + (size_t)r * HC + col0 + tc * 8) =
          make_float4(acc[i][0], acc[i][1], acc[i][2], acc[i][3]);
      *(float4*)(Y + (size_t)r * HC + col0 + tc * 8 + 4) =
          make_float4(acc[i][4], acc[i][5], acc[i][6], acc[i][7]);
    }
  }
}

// ---------------- fused edge score + softmax + aggregate ----------------
// One wave per (node, head-pair). Lane owns a v2f channel pair:
//   wv = wave within node (heads 2wv, 2wv+1); half = lane>>5; head = 2wv+half
//   c = head*64 + (lane&31)*2
// All per-channel math in packed f32 (v_pk_*). Head score reduce: in-register
// pair-add, then 5 xor-stages at width 32 (the 32-lane half IS the head).
// Byte-offset edge records -> near-zero address VALU. Raw-exp softmax via exp2
// with log2(e) folded into att (validated exact r5-r8).
__global__ __launch_bounds__(256, 4) void edge_agg_kernel(
    const float* __restrict__ xl, const float* __restrict__ xr,
    const int* __restrict__ row_ptr, const int2* __restrict__ edg,
    const float* __restrict__ ea, const float* __restrict__ meanea,
    const float* __restrict__ We, const float* __restrict__ att,
    const float* __restrict__ bias, float* __restrict__ out) {
  const int tid = threadIdx.x;
  const int node = blockIdx.x * 2 + (tid >> 7);
  const int lane = tid & 63;
  const int wv = (tid >> 6) & 1;
  const int head = wv * 2 + (lane >> 5);
  const unsigned c = (unsigned)head * CC + (unsigned)(lane & 31) * 2;
  const unsigned cb = c * 4;                    // byte offset of channel pair

  // We columns c,c+1 (adjacent) packed per d
  v2f wreg[16];
#pragma unroll
  for (int d = 0; d < 16; ++d)
    wreg[d] = *(const v2f*)(We + (unsigned)d * HC + c);
  v2f attp = *(const v2f*)(att + c) * 1.44269504088896340736f;  // fold log2(e)
  v2f xrl  = *(const v2f*)(xr + ((unsigned)node << 8) + c);
  // self-loop ee for this channel pair
  v2f seev = {0.f, 0.f};
#pragma unroll
  for (int d = 0; d < 16; ++d) seev += meanea[d] * wreg[d];

  float den = 0.f;
  v2f acc = {0.f, 0.f};
  const int beg = row_ptr[node];
  const int end = row_ptr[node + 1];
  const char* xlb = (const char*)xl;
  const char* eab = (const char*)ea;

  int j = beg;
  // ---- full 8-edge batches ----
  for (; j + 8 <= end; j += 8) {
    int2 E[8];
#pragma unroll
    for (int k = 0; k < 8; ++k) E[k] = edg[(unsigned)(j + k)];
    v2f X[8];
#pragma unroll
    for (int k = 0; k < 8; ++k)
      X[k] = *(const v2f*)(xlb + (unsigned)E[k].y + cb);
    float q[8];
#pragma unroll
    for (int k = 0; k < 8; ++k) {
      v2f ee;
      if (E[k].x >= 0) {                      // wave-uniform branch
        const char* eap = eab + (unsigned)E[k].x;
        v4f a0 = *(const v4f*)(eap);
        v4f a1 = *(const v4f*)(eap + 16);
        v4f a2 = *(const v4f*)(eap + 32);
        v4f a3 = *(const v4f*)(eap + 48);
        ee = a0.x * wreg[0]  + a0.y * wreg[1]  + a0.z * wreg[2]  + a0.w * wreg[3]
           + a1.x * wreg[4]  + a1.y * wreg[5]  + a1.z * wreg[6]  + a1.w * wreg[7]
           + a2.x * wreg[8]  + a2.y * wreg[9]  + a2.z * wreg[10] + a2.w * wreg[11]
           + a3.x * wreg[12] + a3.y * wreg[13] + a3.z * wreg[14] + a3.w * wreg[15];
      } else {
        ee = seev;
      }
      v2f t = X[k] + xrl + ee;
      v2f z = {0.f, 0.f};
      t = __builtin_elementwise_max(t, z) + SLOPE * __builtin_elementwise_min(t, z);
      v2f p = t * attp;
      q[k] = p.x + p.y;                       // pair-add BEFORE shuffles
    }
#pragma unroll
    for (int s = 1; s <= 16; s <<= 1) {
#pragma unroll
      for (int k = 0; k < 8; ++k) q[k] += __shfl_xor(q[k], s, 32);
    }
#pragma unroll
    for (int k = 0; k < 8; ++k) {
      float w = exp2f(q[k]);
      den += w;
      acc += w * X[k];
    }
  }
  // ---- tail batch (clamped) ----
  if (j < end) {
    const int rem = end - j;                  // 1..7
    int2 E[8];
#pragma unroll
    for (int k = 0; k < 8; ++k) E[k] = edg[(unsigned)(j + (k < rem ? k : 0))];
    v2f X[8];
#pragma unroll
    for (int k = 0; k < 8; ++k)
      X[k] = *(const v2f*)(xlb + (unsigned)E[k].y + cb);
    float q[8];
#pragma unroll
    for (int k = 0; k < 8; ++k) {
      v2f ee;
      if (E[k].x >= 0) {
        const char* eap = eab + (unsigned)E[k].x;
        v4f a0 = *(const v4f*)(eap);
        v4f a1 = *(const v4f*)(eap + 16);
        v4f a2 = *(const v4f*)(eap + 32);
        v4f a3 = *(const v4f*)(eap + 48);
        ee = a0.x * wreg[0]  + a0.y * wreg[1]  + a0.z * wreg[2]  + a0.w * wreg[3]
           + a1.x * wreg[4]  + a1.y * wreg[5]  + a1.z * wreg[6]  + a1.w * wreg[7]
           + a2.x * wreg[8]  + a2.y * wreg[9]  + a2.z * wreg[10] + a2.w * wreg[11]
           + a3.x * wreg[12] + a3.y * wreg[13] + a3.z * wreg[14] + a3.w * wreg[15];
      } else {
        ee = seev;
      }
      v2f t = X[k] + xrl + ee;
      v2f z = {0.f, 0.f};
      t = __builtin_elementwise_max(t, z) + SLOPE * __builtin_elementwise_min(t, z);
      v2f p = t * attp;
      q[k] = p.x + p.y;
    }
#pragma unroll
    for (int s = 1; s <= 16; s <<= 1) {
#pragma unroll
      for (int k = 0; k < 8; ++k) q[k] += __shfl_xor(q[k], s, 32);
    }
#pragma unroll
    for (int k = 0; k < 8; ++k) {
      float w = (k < rem) ? exp2f(q[k]) : 0.f;
      den += w;
      acc += w * X[k];
    }
  }
  float inv = 1.f / (den + 1e-16f);
  v2f bp = *(const v2f*)(bias + c);
  v2f o = acc * inv + bp;
  v2f z = {0.f, 0.f};
  o = __builtin_elementwise_max(o, z);        // fused ReLU
  *(v2f*)(out + ((unsigned)node << 8) + c) = o;
}

// ---------------- graph ranges from sorted batch ----------------
__global__ void graph_bounds_kernel(const int* __restrict__ batch, int* __restrict__ gstart) {
  int i = blockIdx.x * blockDim.x + threadIdx.x;
  if (i >= NN) return;
  int b = batch[i];
  int prev = (i == 0) ? -1 : batch[i - 1];
  for (int g = prev + 1; g <= b; ++g) gstart[g] = i;
  if (i == NN - 1)
    for (int g = b + 1; g <= NG; ++g) gstart[g] = NN;
}

// ---------------- global mean pool: one wave per graph ----------------
__global__ void pool_kernel(const float* __restrict__ h2, const int* __restrict__ gstart,
                            float* __restrict__ pooled) {
  int lane = threadIdx.x & 63;
  int g = blockIdx.x * 4 + (threadIdx.x >> 6);
  if (g >= NG) return;
  int s = RFL(gstart[g]), e = RFL(gstart[g + 1]);
  float sx = 0.f, sy = 0.f, sz = 0.f, sw = 0.f;
  for (int i = s; i < e; ++i) {
    float4 v = *(const float4*)(h2 + (size_t)i * HC + lane * 4);
    sx += v.x; sy += v.y; sz += v.z; sw += v.w;
  }
  float inv = 1.f / fmaxf((float)(e - s), 1.f);
  *(float4*)(pooled + (size_t)g * HC + lane * 4) =
      make_float4(sx * inv, sy * inv, sz * inv, sw * inv);
}

// ---------------- final linear: out[g] = pooled_mean . Wf + bf ----------------
__global__ void final_kernel(const float* __restrict__ pooled,
                             const float* __restrict__ Wf, const float* __restrict__ bf,
                             float* __restrict__ out) {
  int lane = threadIdx.x & 63;
  int g = blockIdx.x * (blockDim.x >> 6) + (threadIdx.x >> 6);
  if (g >= NG) return;
  float4 p = *(const float4*)(pooled + (size_t)g * HC + lane * 4);
  float4 w = *(const float4*)(Wf + lane * 4);
  float s = p.x * w.x + p.y * w.y + p.z * w.z + p.w * w.w;
  s += __shfl_xor(s, 1, 64);  s += __shfl_xor(s, 2, 64);
  s += __shfl_xor(s, 4, 64);  s += __shfl_xor(s, 8, 64);
  s += __shfl_xor(s, 16, 64); s += __shfl_xor(s, 32, 64);
  if (lane == 0) out[g] = s + bf[0];
}

extern "C" void kernel_launch(void* const* d_in, const int* in_sizes, int n_in,
                              void* d_out, int out_size, void* d_ws, size_t ws_size,
                              hipStream_t stream) {
  const float* x    = (const float*)d_in[0];
  const int*   ei   = (const int*)d_in[1];   // [2,E]: src row 0, dst row 1
  const int*   batch= (const int*)d_in[2];
  const float* ea   = (const float*)d_in[3];
  const float* Wl1  = (const float*)d_in[4];
  const float* Wr1  = (const float*)d_in[5];
  const float* We1  = (const float*)d_in[6];
  const float* att1 = (const float*)d_in[7];
  const float* b1   = (const float*)d_in[8];
  const float* Wl2  = (const float*)d_in[9];
  const float* Wr2  = (const float*)d_in[10];
  const float* We2  = (const float*)d_in[11];
  const float* att2 = (const float*)d_in[12];
  const float* b2   = (const float*)d_in[13];
  const float* Wf   = (const float*)d_in[14];
  const float* bf   = (const float*)d_in[15];
  float* out = (float*)d_out;

  // workspace layout
  float* xl      = (float*)d_ws;               // N*256
  float* xr      = xl + (size_t)NN * HC;       // N*256
  float* h1      = xr + (size_t)NN * HC;       // N*256
  float* pooled  = h1 + (size_t)NN * HC;       // G*256
  float* meansum = pooled + (size_t)NG * HC;   // 16
  float* meanea  = meansum + 16;               // 16
  int* counts  = (int*)(meanea + 16);          // N
  int* row_ptr = counts + NN;                  // N+1
  int* btot    = row_ptr + NN + 1;             // 256
  int* gstart  = btot + 256;                   // G+1
  int2* edg    = (int2*)(gstart + NG + 1);     // E2 (8B aligned: offset even)

  const int NB = (NN + 255) / 256;             // 196 scan blocks

  hipMemsetAsync(counts, 0, NN * sizeof(int), stream);
  hipMemsetAsync(meansum, 0, 16 * sizeof(float), stream);

  ea_sum_kernel<<<1024, 256, 0, stream>>>(ea, meansum);
  ea_div_kernel<<<1, 16, 0, stream>>>(meansum, meanea);

  count_dst_kernel<<<(NE2 + 255) / 256, 256, 0, stream>>>(ei, counts);
  scan_partial_kernel<<<NB, 256, 0, stream>>>(counts, NN, row_ptr, btot);
  scan_btot_kernel<<<1, 256, 0, stream>>>(btot, NB, row_ptr + NN);
  scan_add_kernel<<<NB, 256, 0, stream>>>(row_ptr, NN, btot);
  hipMemsetAsync(counts, 0, NN * sizeof(int), stream);
  fill_kernel<<<(NE2 + 255) / 256, 256, 0, stream>>>(ei, row_ptr, counts, edg);
  graph_bounds_kernel<<<(NN + 255) / 256, 256, 0, stream>>>(batch, gstart);

  dim3 ggrid((NN + 63) / 64, 2);
  // layer 1
  gemm_kernel<<<ggrid, 256, 0, stream>>>(x, Wl1, xl, NN, INC);
  gemm_kernel<<<ggrid, 256, 0, stream>>>(x, Wr1, xr, NN, INC);
  edge_agg_kernel<<<NN / 2, 256, 0, stream>>>(xl, xr, row_ptr, edg, ea, meanea,
                                              We1, att1, b1, h1);
  // layer 2 (reuse xl/xr buffers)
  gemm_kernel<<<ggrid, 256, 0, stream>>>(h1, Wl2, xl, NN, HC);
  gemm_kernel<<<ggrid, 256, 0, stream>>>(h1, Wr2, xr, NN, HC);
  edge_agg_kernel<<<NN / 2, 256, 0, stream>>>(xl, xr, row_ptr, edg, ea, meanea,
                                              We2, att2, b2, h1);
  // pooling + ffn
  pool_kernel<<<(NG + 3) / 4, 256, 0, stream>>>(h1, gstart, pooled);
  final_kernel<<<(NG + 3) / 4, 256, 0, stream>>>(pooled, Wf, bf, out);
}

// Round 10
// 998.470 us; speedup vs baseline: 1.2298x; 1.2298x over previous
//
#include <hip/hip_runtime.h>
#include <math.h>

// Problem constants (fixed by the reference)
#define NN 50000          // nodes
#define NE 800000         // edges
#define NE2 (NE + NN)     // edges + self loops = 850000
#define INC 64            // in channels
#define EDD 16            // edge dim
#define NH 4              // heads
#define CC 64             // per-head channels
#define HC 256            // H*C
#define NG 2048           // graphs
#define SLOPE 0.2f

typedef float v2f __attribute__((ext_vector_type(2)));
typedef float v4f __attribute__((ext_vector_type(4)));

#define RFL(x) __builtin_amdgcn_readfirstlane(x)

// ---------------- mean edge attr ----------------
__global__ void ea_sum_kernel(const float* __restrict__ ea, float* __restrict__ meansum) {
  __shared__ float part[16];
  if (threadIdx.x < 16) part[threadIdx.x] = 0.f;
  __syncthreads();
  size_t stride = (size_t)gridDim.x * blockDim.x;          // multiple of 16
  size_t i = (size_t)blockIdx.x * blockDim.x + threadIdx.x;
  int cls = (int)(i & 15);                                  // constant along loop
  float s = 0.f;
  const size_t total = (size_t)NE * EDD;
  for (; i < total; i += stride) s += ea[i];
  atomicAdd(&part[cls], s);
  __syncthreads();
  if (threadIdx.x < 16) atomicAdd(&meansum[threadIdx.x], part[threadIdx.x]);
}

__global__ void ea_div_kernel(const float* __restrict__ meansum, float* __restrict__ meanea) {
  if (threadIdx.x < 16) meanea[threadIdx.x] = meansum[threadIdx.x] * (1.0f / NE);
}

// ---------------- CSR build (group edges by dst) ----------------
__global__ void count_dst_kernel(const int* __restrict__ ei, int* __restrict__ counts) {
  int e = blockIdx.x * blockDim.x + threadIdx.x;
  if (e >= NE2) return;
  int d = (e < NE) ? ei[NE + e] : (e - NE);
  atomicAdd(&counts[d], 1);
}

// 3-phase exclusive scan over n counts (n <= 256*256)
__global__ void scan_partial_kernel(const int* __restrict__ counts, int n,
                                    int* __restrict__ excl, int* __restrict__ btot) {
  int b = blockIdx.x;
  int i = b * 256 + threadIdx.x;
  int v = (i < n) ? counts[i] : 0;
  int lane = threadIdx.x & 63;
  int incl = v;
#pragma unroll
  for (int off = 1; off < 64; off <<= 1) {
    int t = __shfl_up(incl, off, 64);
    if (lane >= off) incl += t;
  }
  __shared__ int wtot[4];
  int w = threadIdx.x >> 6;
  if (lane == 63) wtot[w] = incl;
  __syncthreads();
  int woff = 0;
#pragma unroll
  for (int k = 0; k < 4; ++k) woff += (k < w) ? wtot[k] : 0;
  incl += woff;
  if (i < n) excl[i] = incl - v;
  if (threadIdx.x == 255) btot[b] = incl;
}

__global__ void scan_btot_kernel(int* __restrict__ btot, int nb, int* __restrict__ totp) {
  __shared__ int buf[256];
  int v = (threadIdx.x < nb) ? btot[threadIdx.x] : 0;
  buf[threadIdx.x] = v;
  __syncthreads();
  for (int off = 1; off < 256; off <<= 1) {
    int t = (threadIdx.x >= off) ? buf[threadIdx.x - off] : 0;
    __syncthreads();
    buf[threadIdx.x] += t;
    __syncthreads();
  }
  if (threadIdx.x < nb) btot[threadIdx.x] = buf[threadIdx.x] - v;  // exclusive
  if (threadIdx.x == 0) *totp = buf[nb - 1];                       // grand total
}

__global__ void scan_add_kernel(int* __restrict__ excl, int n, const int* __restrict__ btot) {
  int i = blockIdx.x * 256 + threadIdx.x;
  if (i < n) excl[i] += btot[blockIdx.x];
}

__global__ void fill_kernel(const int* __restrict__ ei, const int* __restrict__ row_ptr,
                            int* __restrict__ cursor, int2* __restrict__ edg) {
  int e = blockIdx.x * blockDim.x + threadIdx.x;
  if (e >= NE2) return;
  int d, s;
  if (e < NE) { d = ei[NE + e]; s = ei[e]; }
  else        { d = e - NE;     s = d;     }
  int pos = row_ptr[d] + atomicAdd(&cursor[d], 1);
  edg[pos] = make_int2(e, s);
}

// ---------------- f32 GEMM: [xl|xr] = X @ [Wl|Wr], fused ----------------
// BM=128, BN=128, BK=16, 256 threads, 8x8 per-thread tile.
// grid.y: 0,1 -> Wl cols 0/128 into Yl; 2,3 -> Wr cols 0/128 into Yr.
__global__ __launch_bounds__(256, 2) void gemm2_kernel(
    const float* __restrict__ X,
    const float* __restrict__ Wl, const float* __restrict__ Wr,
    float* __restrict__ Yl, float* __restrict__ Yr, int n, int K) {
  __shared__ float Xs[16][128];
  __shared__ float Ws[16][128];
  const int tid = threadIdx.x;
  const int row0 = blockIdx.x * 128;
  const int quad = blockIdx.y;                 // 0..3
  const float* W = (quad < 2) ? Wl : Wr;
  float* Y = (quad < 2) ? Yl : Yr;
  const int col0 = (quad & 1) * 128;
  const int tr = tid >> 4, tc = tid & 15;      // 16x16 thread grid
  float acc[8][8] = {};
  for (int k0 = 0; k0 < K; k0 += 16) {
    // stage X tile transposed -> Xs[k][m]; 128 rows x 16k, 8 floats/thread
    {
      int m = tid >> 1;                        // 0..127
      int kq = (tid & 1) * 8;                  // 0 or 8
      float4 v0 = make_float4(0.f, 0.f, 0.f, 0.f);
      float4 v1 = make_float4(0.f, 0.f, 0.f, 0.f);
      int r = row0 + m;
      if (r < n) {
        v0 = *(const float4*)(X + (size_t)r * K + k0 + kq);
        v1 = *(const float4*)(X + (size_t)r * K + k0 + kq + 4);
      }
      Xs[kq + 0][m] = v0.x; Xs[kq + 1][m] = v0.y;
      Xs[kq + 2][m] = v0.z; Xs[kq + 3][m] = v0.w;
      Xs[kq + 4][m] = v1.x; Xs[kq + 5][m] = v1.y;
      Xs[kq + 6][m] = v1.z; Xs[kq + 7][m] = v1.w;
    }
    // stage W tile: Ws[k][col]; 16k x 128 cols, 8 floats/thread
    {
      int kk = tid >> 4;                       // 0..15
      int nq = (tid & 15) * 8;                 // 0..120
      float4 w0 = *(const float4*)(W + (size_t)(k0 + kk) * HC + col0 + nq);
      float4 w1 = *(const float4*)(W + (size_t)(k0 + kk) * HC + col0 + nq + 4);
      *(float4*)(&Ws[kk][nq])     = w0;
      *(float4*)(&Ws[kk][nq + 4]) = w1;
    }
    __syncthreads();
#pragma unroll
    for (int k = 0; k < 16; ++k) {
      float a[8], b[8];
      *(float4*)(a)     = *(const float4*)(&Xs[k][tr * 8]);
      *(float4*)(a + 4) = *(const float4*)(&Xs[k][tr * 8 + 4]);
      *(float4*)(b)     = *(const float4*)(&Ws[k][tc * 8]);
      *(float4*)(b + 4) = *(const float4*)(&Ws[k][tc * 8 + 4]);
#pragma unroll
      for (int i = 0; i < 8; ++i)
#pragma unroll
        for (int jj = 0; jj < 8; ++jj) acc[i][jj] += a[i] * b[jj];
    }
    __syncthreads();
  }
#pragma unroll
  for (int i = 0; i < 8; ++i) {
    int r = row0 + tr * 8 + i;
    if (r < n) {
      *(float4*)(Y + (size_t)r * HC + col0 + tc * 8) =
          make_float4(acc[i][0], acc[i][1], acc[i][2], acc[i][3]);
      *(float4*)(Y + (size_t)r * HC + col0 + tc * 8 + 4) =
          make_float4(acc[i][4], acc[i][5], acc[i][6], acc[i][7]);
    }
  }
}

// ---------------- fused edge score + softmax + aggregate (r8 winner) ----------------
// One wave per (node, head). Lane owns ONE channel c = head*64 + lane.
// Per-lane state: We column as 8 v2f pairs, att (1), xr (1), self-ee (1).
// ee-dot in packed f32; 32-bit element-offset addressing; exp2 with log2(e)
// folded into att; raw-exp softmax (validated r5-r8).
__global__ __launch_bounds__(256, 4) void edge_agg_kernel(
    const float* __restrict__ xl, const float* __restrict__ xr,
    const int* __restrict__ row_ptr, const int2* __restrict__ edg,
    const float* __restrict__ ea, const float* __restrict__ meanea,
    const float* __restrict__ We, const float* __restrict__ att,
    const float* __restrict__ bias, float* __restrict__ out) {
  const int lane = threadIdx.x & 63;
  const int head = threadIdx.x >> 6;          // 0..3
  const int node = blockIdx.x;
  const unsigned c = (unsigned)head * CC + (unsigned)lane;   // channel 0..255

  // per-lane column of We, packed as pairs over d
  v2f wreg[8];
#pragma unroll
  for (int d = 0; d < 8; ++d)
    wreg[d] = (v2f){We[(unsigned)(2 * d) * HC + c], We[(unsigned)(2 * d + 1) * HC + c]};
  const float attl = att[c] * 1.44269504088896340736f;   // fold log2(e): exp(q)=2^(q*log2e)
  const float xrl  = xr[((unsigned)node << 8) + c];
  // self-loop ee for this channel (mean edge attr @ We column)
  v2f seev = {0.f, 0.f};
#pragma unroll
  for (int d = 0; d < 8; ++d)
    seev += (v2f){meanea[2 * d], meanea[2 * d + 1]} * wreg[d];
  const float see = seev.x + seev.y;

  float den = 0.f, acc = 0.f;
  const int beg = row_ptr[node];
  const int end = row_ptr[node + 1];

  int j = beg;
  // ---- full 8-edge batches: no clamping ----
  for (; j + 8 <= end; j += 8) {
    int2 E[8];
#pragma unroll
    for (int k = 0; k < 8; ++k) E[k] = edg[(unsigned)(j + k)];
    float X[8];
#pragma unroll
    for (int k = 0; k < 8; ++k) X[k] = xl[((unsigned)E[k].y << 8) + c];
    float q[8];
#pragma unroll
    for (int k = 0; k < 8; ++k) {
      float ee;
      if (E[k].x < NE) {
        const float* eap = ea + ((size_t)((unsigned)E[k].x << 4));
        v4f a0 = *(const v4f*)(eap);
        v4f a1 = *(const v4f*)(eap + 4);
        v4f a2 = *(const v4f*)(eap + 8);
        v4f a3 = *(const v4f*)(eap + 12);
        v2f s = (v2f){a0.x, a0.y} * wreg[0] + (v2f){a0.z, a0.w} * wreg[1]
              + (v2f){a1.x, a1.y} * wreg[2] + (v2f){a1.z, a1.w} * wreg[3]
              + (v2f){a2.x, a2.y} * wreg[4] + (v2f){a2.z, a2.w} * wreg[5]
              + (v2f){a3.x, a3.y} * wreg[6] + (v2f){a3.z, a3.w} * wreg[7];
        ee = s.x + s.y;
      } else {
        ee = see;
      }
      float t = X[k] + xrl + ee;
      t = (t > 0.f) ? t : SLOPE * t;
      q[k] = t * attl;
    }
#pragma unroll
    for (int s = 1; s <= 32; s <<= 1) {
#pragma unroll
      for (int k = 0; k < 8; ++k) q[k] += __shfl_xor(q[k], s, 64);
    }
#pragma unroll
    for (int k = 0; k < 8; ++k) {
      float w = exp2f(q[k]);
      den += w;
      acc = fmaf(w, X[k], acc);
    }
  }
  // ---- tail batch (clamped) ----
  if (j < end) {
    const int rem = end - j;                  // 1..7
    int2 E[8];
#pragma unroll
    for (int k = 0; k < 8; ++k) E[k] = edg[(unsigned)(j + (k < rem ? k : 0))];
    float X[8];
#pragma unroll
    for (int k = 0; k < 8; ++k) X[k] = xl[((unsigned)E[k].y << 8) + c];
    float q[8];
#pragma unroll
    for (int k = 0; k < 8; ++k) {
      float ee;
      if (E[k].x < NE) {
        const float* eap = ea + ((size_t)((unsigned)E[k].x << 4));
        v4f a0 = *(const v4f*)(eap);
        v4f a1 = *(const v4f*)(eap + 4);
        v4f a2 = *(const v4f*)(eap + 8);
        v4f a3 = *(const v4f*)(eap + 12);
        v2f s = (v2f){a0.x, a0.y} * wreg[0] + (v2f){a0.z, a0.w} * wreg[1]
              + (v2f){a1.x, a1.y} * wreg[2] + (v2f){a1.z, a1.w} * wreg[3]
              + (v2f){a2.x, a2.y} * wreg[4] + (v2f){a2.z, a2.w} * wreg[5]
              + (v2f){a3.x, a3.y} * wreg[6] + (v2f){a3.z, a3.w} * wreg[7];
        ee = s.x + s.y;
      } else {
        ee = see;
      }
      float t = X[k] + xrl + ee;
      t = (t > 0.f) ? t : SLOPE * t;
      q[k] = t * attl;
    }
#pragma unroll
    for (int s = 1; s <= 32; s <<= 1) {
#pragma unroll
      for (int k = 0; k < 8; ++k) q[k] += __shfl_xor(q[k], s, 64);
    }
#pragma unroll
    for (int k = 0; k < 8; ++k) {
      float w = (k < rem) ? exp2f(q[k]) : 0.f;
      den += w;
      acc = fmaf(w, X[k], acc);
    }
  }
  float o = fmaxf(acc / (den + 1e-16f) + bias[c], 0.f);   // fused ReLU
  out[((unsigned)node << 8) + c] = o;
}

// ---------------- graph ranges from sorted batch ----------------
__global__ void graph_bounds_kernel(const int* __restrict__ batch, int* __restrict__ gstart) {
  int i = blockIdx.x * blockDim.x + threadIdx.x;
  if (i >= NN) return;
  int b = batch[i];
  int prev = (i == 0) ? -1 : batch[i - 1];
  for (int g = prev + 1; g <= b; ++g) gstart[g] = i;
  if (i == NN - 1)
    for (int g = b + 1; g <= NG; ++g) gstart[g] = NN;
}

// ---------------- global mean pool: one wave per graph ----------------
__global__ void pool_kernel(const float* __restrict__ h2, const int* __restrict__ gstart,
                            float* __restrict__ pooled) {
  int lane = threadIdx.x & 63;
  int g = blockIdx.x * 4 + (threadIdx.x >> 6);
  if (g >= NG) return;
  int s = RFL(gstart[g]), e = RFL(gstart[g + 1]);
  float sx = 0.f, sy = 0.f, sz = 0.f, sw = 0.f;
  for (int i = s; i < e; ++i) {
    float4 v = *(const float4*)(h2 + (size_t)i * HC + lane * 4);
    sx += v.x; sy += v.y; sz += v.z; sw += v.w;
  }
  float inv = 1.f / fmaxf((float)(e - s), 1.f);
  *(float4*)(pooled + (size_t)g * HC + lane * 4) =
      make_float4(sx * inv, sy * inv, sz * inv, sw * inv);
}

// ---------------- final linear: out[g] = pooled_mean . Wf + bf ----------------
__global__ void final_kernel(const float* __restrict__ pooled,
                             const float* __restrict__ Wf, const float* __restrict__ bf,
                             float* __restrict__ out) {
  int lane = threadIdx.x & 63;
  int g = blockIdx.x * (blockDim.x >> 6) + (threadIdx.x >> 6);
  if (g >= NG) return;
  float4 p = *(const float4*)(pooled + (size_t)g * HC + lane * 4);
  float4 w = *(const float4*)(Wf + lane * 4);
  float s = p.x * w.x + p.y * w.y + p.z * w.z + p.w * w.w;
  s += __shfl_xor(s, 1, 64);  s += __shfl_xor(s, 2, 64);
  s += __shfl_xor(s, 4, 64);  s += __shfl_xor(s, 8, 64);
  s += __shfl_xor(s, 16, 64); s += __shfl_xor(s, 32, 64);
  if (lane == 0) out[g] = s + bf[0];
}

extern "C" void kernel_launch(void* const* d_in, const int* in_sizes, int n_in,
                              void* d_out, int out_size, void* d_ws, size_t ws_size,
                              hipStream_t stream) {
  const float* x    = (const float*)d_in[0];
  const int*   ei   = (const int*)d_in[1];   // [2,E]: src row 0, dst row 1
  const int*   batch= (const int*)d_in[2];
  const float* ea   = (const float*)d_in[3];
  const float* Wl1  = (const float*)d_in[4];
  const float* Wr1  = (const float*)d_in[5];
  const float* We1  = (const float*)d_in[6];
  const float* att1 = (const float*)d_in[7];
  const float* b1   = (const float*)d_in[8];
  const float* Wl2  = (const float*)d_in[9];
  const float* Wr2  = (const float*)d_in[10];
  const float* We2  = (const float*)d_in[11];
  const float* att2 = (const float*)d_in[12];
  const float* b2   = (const float*)d_in[13];
  const float* Wf   = (const float*)d_in[14];
  const float* bf   = (const float*)d_in[15];
  float* out = (float*)d_out;

  // workspace layout
  float* xl      = (float*)d_ws;               // N*256
  float* xr      = xl + (size_t)NN * HC;       // N*256
  float* h1      = xr + (size_t)NN * HC;       // N*256
  float* pooled  = h1 + (size_t)NN * HC;       // G*256
  float* meansum = pooled + (size_t)NG * HC;   // 16
  float* meanea  = meansum + 16;               // 16
  int* counts  = (int*)(meanea + 16);          // N
  int* row_ptr = counts + NN;                  // N+1
  int* btot    = row_ptr + NN + 1;             // 256
  int* gstart  = btot + 256;                   // G+1
  int2* edg    = (int2*)(gstart + NG + 1);     // E2 (8B aligned: offset even)

  const int NB = (NN + 255) / 256;             // 196 scan blocks

  hipMemsetAsync(counts, 0, NN * sizeof(int), stream);
  hipMemsetAsync(meansum, 0, 16 * sizeof(float), stream);

  ea_sum_kernel<<<1024, 256, 0, stream>>>(ea, meansum);
  ea_div_kernel<<<1, 16, 0, stream>>>(meansum, meanea);

  count_dst_kernel<<<(NE2 + 255) / 256, 256, 0, stream>>>(ei, counts);
  scan_partial_kernel<<<NB, 256, 0, stream>>>(counts, NN, row_ptr, btot);
  scan_btot_kernel<<<1, 256, 0, stream>>>(btot, NB, row_ptr + NN);
  scan_add_kernel<<<NB, 256, 0, stream>>>(row_ptr, NN, btot);
  hipMemsetAsync(counts, 0, NN * sizeof(int), stream);
  fill_kernel<<<(NE2 + 255) / 256, 256, 0, stream>>>(ei, row_ptr, counts, edg);
  graph_bounds_kernel<<<(NN + 255) / 256, 256, 0, stream>>>(batch, gstart);

  dim3 ggrid((NN + 127) / 128, 4);
  // layer 1 (fused Wl|Wr GEMM)
  gemm2_kernel<<<ggrid, 256, 0, stream>>>(x, Wl1, Wr1, xl, xr, NN, INC);
  edge_agg_kernel<<<NN, 256, 0, stream>>>(xl, xr, row_ptr, edg, ea, meanea,
                                          We1, att1, b1, h1);
  // layer 2 (reuse xl/xr buffers)
  gemm2_kernel<<<ggrid, 256, 0, stream>>>(h1, Wl2, Wr2, xl, xr, NN, HC);
  edge_agg_kernel<<<NN, 256, 0, stream>>>(xl, xr, row_ptr, edg, ea, meanea,
                                          We2, att2, b2, h1);
  // pooling + ffn
  pool_kernel<<<(NG + 3) / 4, 256, 0, stream>>>(h1, gstart, pooled);
  final_kernel<<<(NG + 3) / 4, 256, 0, stream>>>(pooled, Wf, bf, out);
}

// Round 11
// 982.800 us; speedup vs baseline: 1.2494x; 1.0159x over previous
//
#include <hip/hip_runtime.h>
#include <math.h>

// Problem constants (fixed by the reference)
#define NN 50000          // nodes
#define NE 800000         // edges
#define NE2 (NE + NN)     // edges + self loops = 850000
#define INC 64            // in channels
#define EDD 16            // edge dim
#define NH 4              // heads
#define CC 64             // per-head channels
#define HC 256            // H*C
#define NG 2048           // graphs
#define SLOPE 0.2f

typedef float v2f __attribute__((ext_vector_type(2)));
typedef float v4f __attribute__((ext_vector_type(4)));

#define RFL(x) __builtin_amdgcn_readfirstlane(x)

// ---------------- DPP wave-64 sum (VALU pipe, no DS traffic) ----------------
// After the 6 stages lane 63 holds the full 64-lane sum; readlane broadcasts.
template <int CTRL, int RM>
__device__ __forceinline__ float dpp_add(float x) {
  int t = __builtin_amdgcn_update_dpp(0, __builtin_bit_cast(int, x),
                                      CTRL, RM, 0xF, false);
  return x + __builtin_bit_cast(float, t);
}
__device__ __forceinline__ float wave_sum_bcast(float x) {
  x = dpp_add<0x111, 0xF>(x);   // row_shr:1
  x = dpp_add<0x112, 0xF>(x);   // row_shr:2
  x = dpp_add<0x114, 0xF>(x);   // row_shr:4
  x = dpp_add<0x118, 0xF>(x);   // row_shr:8  -> lane15/31/47/63 = row sums
  x = dpp_add<0x142, 0xA>(x);   // row_bcast:15 -> lane31/63 = 2-row sums
  x = dpp_add<0x143, 0xC>(x);   // row_bcast:31 -> lane63 = full sum
  return __builtin_bit_cast(float,
      __builtin_amdgcn_readlane(__builtin_bit_cast(int, x), 63));
}

// ---------------- mean edge attr ----------------
__global__ void ea_sum_kernel(const float* __restrict__ ea, float* __restrict__ meansum) {
  __shared__ float part[16];
  if (threadIdx.x < 16) part[threadIdx.x] = 0.f;
  __syncthreads();
  size_t stride = (size_t)gridDim.x * blockDim.x;          // multiple of 16
  size_t i = (size_t)blockIdx.x * blockDim.x + threadIdx.x;
  int cls = (int)(i & 15);                                  // constant along loop
  float s = 0.f;
  const size_t total = (size_t)NE * EDD;
  for (; i < total; i += stride) s += ea[i];
  atomicAdd(&part[cls], s);
  __syncthreads();
  if (threadIdx.x < 16) atomicAdd(&meansum[threadIdx.x], part[threadIdx.x]);
}

__global__ void ea_div_kernel(const float* __restrict__ meansum, float* __restrict__ meanea) {
  if (threadIdx.x < 16) meanea[threadIdx.x] = meansum[threadIdx.x] * (1.0f / NE);
}

// ---------------- CSR build (group edges by dst) ----------------
__global__ void count_dst_kernel(const int* __restrict__ ei, int* __restrict__ counts) {
  int e = blockIdx.x * blockDim.x + threadIdx.x;
  if (e >= NE2) return;
  int d = (e < NE) ? ei[NE + e] : (e - NE);
  atomicAdd(&counts[d], 1);
}

// 3-phase exclusive scan over n counts (n <= 256*256)
__global__ void scan_partial_kernel(const int* __restrict__ counts, int n,
                                    int* __restrict__ excl, int* __restrict__ btot) {
  int b = blockIdx.x;
  int i = b * 256 + threadIdx.x;
  int v = (i < n) ? counts[i] : 0;
  int lane = threadIdx.x & 63;
  int incl = v;
#pragma unroll
  for (int off = 1; off < 64; off <<= 1) {
    int t = __shfl_up(incl, off, 64);
    if (lane >= off) incl += t;
  }
  __shared__ int wtot[4];
  int w = threadIdx.x >> 6;
  if (lane == 63) wtot[w] = incl;
  __syncthreads();
  int woff = 0;
#pragma unroll
  for (int k = 0; k < 4; ++k) woff += (k < w) ? wtot[k] : 0;
  incl += woff;
  if (i < n) excl[i] = incl - v;
  if (threadIdx.x == 255) btot[b] = incl;
}

__global__ void scan_btot_kernel(int* __restrict__ btot, int nb, int* __restrict__ totp) {
  __shared__ int buf[256];
  int v = (threadIdx.x < nb) ? btot[threadIdx.x] : 0;
  buf[threadIdx.x] = v;
  __syncthreads();
  for (int off = 1; off < 256; off <<= 1) {
    int t = (threadIdx.x >= off) ? buf[threadIdx.x - off] : 0;
    __syncthreads();
    buf[threadIdx.x] += t;
    __syncthreads();
  }
  if (threadIdx.x < nb) btot[threadIdx.x] = buf[threadIdx.x] - v;  // exclusive
  if (threadIdx.x == 0) *totp = buf[nb - 1];                       // grand total
}

__global__ void scan_add_kernel(int* __restrict__ excl, int n, const int* __restrict__ btot) {
  int i = blockIdx.x * 256 + threadIdx.x;
  if (i < n) excl[i] += btot[blockIdx.x];
}

__global__ void fill_kernel(const int* __restrict__ ei, const int* __restrict__ row_ptr,
                            int* __restrict__ cursor, int2* __restrict__ edg) {
  int e = blockIdx.x * blockDim.x + threadIdx.x;
  if (e >= NE2) return;
  int d, s;
  if (e < NE) { d = ei[NE + e]; s = ei[e]; }
  else        { d = e - NE;     s = d;     }
  int pos = row_ptr[d] + atomicAdd(&cursor[d], 1);
  edg[pos] = make_int2(e, s);
}

// ---------------- f32 GEMM: [xl|xr] = X @ [Wl|Wr], fused ----------------
// BM=128, BN=128, BK=16, 256 threads, 8x8 per-thread tile.
// grid.y: 0,1 -> Wl cols 0/128 into Yl; 2,3 -> Wr cols 0/128 into Yr.
__global__ __launch_bounds__(256, 2) void gemm2_kernel(
    const float* __restrict__ X,
    const float* __restrict__ Wl, const float* __restrict__ Wr,
    float* __restrict__ Yl, float* __restrict__ Yr, int n, int K) {
  __shared__ float Xs[16][128];
  __shared__ float Ws[16][128];
  const int tid = threadIdx.x;
  const int row0 = blockIdx.x * 128;
  const int quad = blockIdx.y;                 // 0..3
  const float* W = (quad < 2) ? Wl : Wr;
  float* Y = (quad < 2) ? Yl : Yr;
  const int col0 = (quad & 1) * 128;
  const int tr = tid >> 4, tc = tid & 15;      // 16x16 thread grid
  float acc[8][8] = {};
  for (int k0 = 0; k0 < K; k0 += 16) {
    // stage X tile transposed -> Xs[k][m]; 128 rows x 16k, 8 floats/thread
    {
      int m = tid >> 1;                        // 0..127
      int kq = (tid & 1) * 8;                  // 0 or 8
      float4 v0 = make_float4(0.f, 0.f, 0.f, 0.f);
      float4 v1 = make_float4(0.f, 0.f, 0.f, 0.f);
      int r = row0 + m;
      if (r < n) {
        v0 = *(const float4*)(X + (size_t)r * K + k0 + kq);
        v1 = *(const float4*)(X + (size_t)r * K + k0 + kq + 4);
      }
      Xs[kq + 0][m] = v0.x; Xs[kq + 1][m] = v0.y;
      Xs[kq + 2][m] = v0.z; Xs[kq + 3][m] = v0.w;
      Xs[kq + 4][m] = v1.x; Xs[kq + 5][m] = v1.y;
      Xs[kq + 6][m] = v1.z; Xs[kq + 7][m] = v1.w;
    }
    // stage W tile: Ws[k][col]; 16k x 128 cols, 8 floats/thread
    {
      int kk = tid >> 4;                       // 0..15
      int nq = (tid & 15) * 8;                 // 0..120
      float4 w0 = *(const float4*)(W + (size_t)(k0 + kk) * HC + col0 + nq);
      float4 w1 = *(const float4*)(W + (size_t)(k0 + kk) * HC + col0 + nq + 4);
      *(float4*)(&Ws[kk][nq])     = w0;
      *(float4*)(&Ws[kk][nq + 4]) = w1;
    }
    __syncthreads();
#pragma unroll
    for (int k = 0; k < 16; ++k) {
      float a[8], b[8];
      *(float4*)(a)     = *(const float4*)(&Xs[k][tr * 8]);
      *(float4*)(a + 4) = *(const float4*)(&Xs[k][tr * 8 + 4]);
      *(float4*)(b)     = *(const float4*)(&Ws[k][tc * 8]);
      *(float4*)(b + 4) = *(const float4*)(&Ws[k][tc * 8 + 4]);
#pragma unroll
      for (int i = 0; i < 8; ++i)
#pragma unroll
        for (int jj = 0; jj < 8; ++jj) acc[i][jj] += a[i] * b[jj];
    }
    __syncthreads();
  }
#pragma unroll
  for (int i = 0; i < 8; ++i) {
    int r = row0 + tr * 8 + i;
    if (r < n) {
      *(float4*)(Y + (size_t)r * HC + col0 + tc * 8) =
          make_float4(acc[i][0], acc[i][1], acc[i][2], acc[i][3]);
      *(float4*)(Y + (size_t)r * HC + col0 + tc * 8 + 4) =
          make_float4(acc[i][4], acc[i][5], acc[i][6], acc[i][7]);
    }
  }
}

// ---------------- fused edge score + softmax + aggregate ----------------
// r8/r10 structure (one wave per (node, head), lane owns one channel) with the
// 64-lane score reduction moved from DS shuffles to VALU DPP (wave_sum_bcast).
__global__ __launch_bounds__(256, 4) void edge_agg_kernel(
    const float* __restrict__ xl, const float* __restrict__ xr,
    const int* __restrict__ row_ptr, const int2* __restrict__ edg,
    const float* __restrict__ ea, const float* __restrict__ meanea,
    const float* __restrict__ We, const float* __restrict__ att,
    const float* __restrict__ bias, float* __restrict__ out) {
  const int lane = threadIdx.x & 63;
  const int head = threadIdx.x >> 6;          // 0..3
  const int node = blockIdx.x;
  const unsigned c = (unsigned)head * CC + (unsigned)lane;   // channel 0..255

  // per-lane column of We, packed as pairs over d
  v2f wreg[8];
#pragma unroll
  for (int d = 0; d < 8; ++d)
    wreg[d] = (v2f){We[(unsigned)(2 * d) * HC + c], We[(unsigned)(2 * d + 1) * HC + c]};
  const float attl = att[c] * 1.44269504088896340736f;   // fold log2(e): exp(q)=2^(q*log2e)
  const float xrl  = xr[((unsigned)node << 8) + c];
  // self-loop ee for this channel (mean edge attr @ We column)
  v2f seev = {0.f, 0.f};
#pragma unroll
  for (int d = 0; d < 8; ++d)
    seev += (v2f){meanea[2 * d], meanea[2 * d + 1]} * wreg[d];
  const float see = seev.x + seev.y;

  float den = 0.f, acc = 0.f;
  const int beg = row_ptr[node];
  const int end = row_ptr[node + 1];

  int j = beg;
  // ---- full 8-edge batches: no clamping ----
  for (; j + 8 <= end; j += 8) {
    int2 E[8];
#pragma unroll
    for (int k = 0; k < 8; ++k) E[k] = edg[(unsigned)(j + k)];
    float X[8];
#pragma unroll
    for (int k = 0; k < 8; ++k) X[k] = xl[((unsigned)E[k].y << 8) + c];
    float q[8];
#pragma unroll
    for (int k = 0; k < 8; ++k) {
      float ee;
      if (E[k].x < NE) {
        const float* eap = ea + ((size_t)((unsigned)E[k].x << 4));
        v4f a0 = *(const v4f*)(eap);
        v4f a1 = *(const v4f*)(eap + 4);
        v4f a2 = *(const v4f*)(eap + 8);
        v4f a3 = *(const v4f*)(eap + 12);
        v2f s = (v2f){a0.x, a0.y} * wreg[0] + (v2f){a0.z, a0.w} * wreg[1]
              + (v2f){a1.x, a1.y} * wreg[2] + (v2f){a1.z, a1.w} * wreg[3]
              + (v2f){a2.x, a2.y} * wreg[4] + (v2f){a2.z, a2.w} * wreg[5]
              + (v2f){a3.x, a3.y} * wreg[6] + (v2f){a3.z, a3.w} * wreg[7];
        ee = s.x + s.y;
      } else {
        ee = see;
      }
      float t = X[k] + xrl + ee;
      t = (t > 0.f) ? t : SLOPE * t;
      q[k] = t * attl;
    }
    // 8 independent DPP reductions (VALU pipe)
#pragma unroll
    for (int k = 0; k < 8; ++k) q[k] = wave_sum_bcast(q[k]);
#pragma unroll
    for (int k = 0; k < 8; ++k) {
      float w = exp2f(q[k]);
      den += w;
      acc = fmaf(w, X[k], acc);
    }
  }
  // ---- tail batch (clamped) ----
  if (j < end) {
    const int rem = end - j;                  // 1..7
    int2 E[8];
#pragma unroll
    for (int k = 0; k < 8; ++k) E[k] = edg[(unsigned)(j + (k < rem ? k : 0))];
    float X[8];
#pragma unroll
    for (int k = 0; k < 8; ++k) X[k] = xl[((unsigned)E[k].y << 8) + c];
    float q[8];
#pragma unroll
    for (int k = 0; k < 8; ++k) {
      float ee;
      if (E[k].x < NE) {
        const float* eap = ea + ((size_t)((unsigned)E[k].x << 4));
        v4f a0 = *(const v4f*)(eap);
        v4f a1 = *(const v4f*)(eap + 4);
        v4f a2 = *(const v4f*)(eap + 8);
        v4f a3 = *(const v4f*)(eap + 12);
        v2f s = (v2f){a0.x, a0.y} * wreg[0] + (v2f){a0.z, a0.w} * wreg[1]
              + (v2f){a1.x, a1.y} * wreg[2] + (v2f){a1.z, a1.w} * wreg[3]
              + (v2f){a2.x, a2.y} * wreg[4] + (v2f){a2.z, a2.w} * wreg[5]
              + (v2f){a3.x, a3.y} * wreg[6] + (v2f){a3.z, a3.w} * wreg[7];
        ee = s.x + s.y;
      } else {
        ee = see;
      }
      float t = X[k] + xrl + ee;
      t = (t > 0.f) ? t : SLOPE * t;
      q[k] = t * attl;
    }
#pragma unroll
    for (int k = 0; k < 8; ++k) q[k] = wave_sum_bcast(q[k]);
#pragma unroll
    for (int k = 0; k < 8; ++k) {
      float w = (k < rem) ? exp2f(q[k]) : 0.f;
      den += w;
      acc = fmaf(w, X[k], acc);
    }
  }
  float o = fmaxf(acc / (den + 1e-16f) + bias[c], 0.f);   // fused ReLU
  out[((unsigned)node << 8) + c] = o;
}

// ---------------- graph ranges from sorted batch ----------------
__global__ void graph_bounds_kernel(const int* __restrict__ batch, int* __restrict__ gstart) {
  int i = blockIdx.x * blockDim.x + threadIdx.x;
  if (i >= NN) return;
  int b = batch[i];
  int prev = (i == 0) ? -1 : batch[i - 1];
  for (int g = prev + 1; g <= b; ++g) gstart[g] = i;
  if (i == NN - 1)
    for (int g = b + 1; g <= NG; ++g) gstart[g] = NN;
}

// ---------------- global mean pool: one wave per graph ----------------
__global__ void pool_kernel(const float* __restrict__ h2, const int* __restrict__ gstart,
                            float* __restrict__ pooled) {
  int lane = threadIdx.x & 63;
  int g = blockIdx.x * 4 + (threadIdx.x >> 6);
  if (g >= NG) return;
  int s = RFL(gstart[g]), e = RFL(gstart[g + 1]);
  float sx = 0.f, sy = 0.f, sz = 0.f, sw = 0.f;
  for (int i = s; i < e; ++i) {
    float4 v = *(const float4*)(h2 + (size_t)i * HC + lane * 4);
    sx += v.x; sy += v.y; sz += v.z; sw += v.w;
  }
  float inv = 1.f / fmaxf((float)(e - s), 1.f);
  *(float4*)(pooled + (size_t)g * HC + lane * 4) =
      make_float4(sx * inv, sy * inv, sz * inv, sw * inv);
}

// ---------------- final linear: out[g] = pooled_mean . Wf + bf ----------------
__global__ void final_kernel(const float* __restrict__ pooled,
                             const float* __restrict__ Wf, const float* __restrict__ bf,
                             float* __restrict__ out) {
  int lane = threadIdx.x & 63;
  int g = blockIdx.x * (blockDim.x >> 6) + (threadIdx.x >> 6);
  if (g >= NG) return;
  float4 p = *(const float4*)(pooled + (size_t)g * HC + lane * 4);
  float4 w = *(const float4*)(Wf + lane * 4);
  float s = p.x * w.x + p.y * w.y + p.z * w.z + p.w * w.w;
  s += __shfl_xor(s, 1, 64);  s += __shfl_xor(s, 2, 64);
  s += __shfl_xor(s, 4, 64);  s += __shfl_xor(s, 8, 64);
  s += __shfl_xor(s, 16, 64); s += __shfl_xor(s, 32, 64);
  if (lane == 0) out[g] = s + bf[0];
}

extern "C" void kernel_launch(void* const* d_in, const int* in_sizes, int n_in,
                              void* d_out, int out_size, void* d_ws, size_t ws_size,
                              hipStream_t stream) {
  const float* x    = (const float*)d_in[0];
  const int*   ei   = (const int*)d_in[1];   // [2,E]: src row 0, dst row 1
  const int*   batch= (const int*)d_in[2];
  const float* ea   = (const float*)d_in[3];
  const float* Wl1  = (const float*)d_in[4];
  const float* Wr1  = (const float*)d_in[5];
  const float* We1  = (const float*)d_in[6];
  const float* att1 = (const float*)d_in[7];
  const float* b1   = (const float*)d_in[8];
  const float* Wl2  = (const float*)d_in[9];
  const float* Wr2  = (const float*)d_in[10];
  const float* We2  = (const float*)d_in[11];
  const float* att2 = (const float*)d_in[12];
  const float* b2   = (const float*)d_in[13];
  const float* Wf   = (const float*)d_in[14];
  const float* bf   = (const float*)d_in[15];
  float* out = (float*)d_out;

  // workspace layout
  float* xl      = (float*)d_ws;               // N*256
  float* xr      = xl + (size_t)NN * HC;       // N*256
  float* h1      = xr + (size_t)NN * HC;       // N*256
  float* pooled  = h1 + (size_t)NN * HC;       // G*256
  float* meansum = pooled + (size_t)NG * HC;   // 16
  float* meanea  = meansum + 16;               // 16
  int* counts  = (int*)(meanea + 16);          // N
  int* row_ptr = counts + NN;                  // N+1
  int* btot    = row_ptr + NN + 1;             // 256
  int* gstart  = btot + 256;                   // G+1
  int2* edg    = (int2*)(gstart + NG + 1);     // E2 (8B aligned: offset even)

  const int NB = (NN + 255) / 256;             // 196 scan blocks

  hipMemsetAsync(counts, 0, NN * sizeof(int), stream);
  hipMemsetAsync(meansum, 0, 16 * sizeof(float), stream);

  ea_sum_kernel<<<1024, 256, 0, stream>>>(ea, meansum);
  ea_div_kernel<<<1, 16, 0, stream>>>(meansum, meanea);

  count_dst_kernel<<<(NE2 + 255) / 256, 256, 0, stream>>>(ei, counts);
  scan_partial_kernel<<<NB, 256, 0, stream>>>(counts, NN, row_ptr, btot);
  scan_btot_kernel<<<1, 256, 0, stream>>>(btot, NB, row_ptr + NN);
  scan_add_kernel<<<NB, 256, 0, stream>>>(row_ptr, NN, btot);
  hipMemsetAsync(counts, 0, NN * sizeof(int), stream);
  fill_kernel<<<(NE2 + 255) / 256, 256, 0, stream>>>(ei, row_ptr, counts, edg);
  graph_bounds_kernel<<<(NN + 255) / 256, 256, 0, stream>>>(batch, gstart);

  dim3 ggrid((NN + 127) / 128, 4);
  // layer 1 (fused Wl|Wr GEMM)
  gemm2_kernel<<<ggrid, 256, 0, stream>>>(x, Wl1, Wr1, xl, xr, NN, INC);
  edge_agg_kernel<<<NN, 256, 0, stream>>>(xl, xr, row_ptr, edg, ea, meanea,
                                          We1, att1, b1, h1);
  // layer 2 (reuse xl/xr buffers)
  gemm2_kernel<<<ggrid, 256, 0, stream>>>(h1, Wl2, Wr2, xl, xr, NN, HC);
  edge_agg_kernel<<<NN, 256, 0, stream>>>(xl, xr, row_ptr, edg, ea, meanea,
                                          We2, att2, b2, h1);
  // pooling + ffn
  pool_kernel<<<(NG + 3) / 4, 256, 0, stream>>>(h1, gstart, pooled);
  final_kernel<<<(NG + 3) / 4, 256, 0, stream>>>(pooled, Wf, bf, out);
}